// Round 1
// 2893.777 us; speedup vs baseline: 1.1782x; 1.1782x over previous
//
#include <hip/hip_runtime.h>
#include <stdint.h>

// 3-layer LSTM (H=64, B=256, S=4096, DIN=1) + linear head.
// One block/batch element; 768 thr = 3 groups of 256 (group = layer), skewed
// pipeline (tick T: l0@T, l1@T-1, l2@T-2, y@T-3). Col-split matvec: thread
// (u,qt) does all 4 gate rows of unit u over col quarter qt.
//
// R8: VGPR=48 in R7 proved weights STILL not register-resident: the compiler
// re-runs load+cvt+pack in-loop (~144 VALU/thread/tick, matches the measured
// VALUBusy excess; loads hit L1/L2 so FETCH_SIZE doesn't show it).
// Fixes: (1) prep kernel pre-packs fp16-pair weights into d_ws in per-thread
// streaming order -> main-kernel weight init is pure dwordx4 loads, nothing
// left to rematerialize; (2) weights stored in XOR gate-row order
// (seg i = row (qt^i)*64+u) -> quad reduce is add-only DPP (no cndmask);
// (3) raw v_rcp/v_exp for sigmoid+tanh (no precise-div expansion).

#define SQ 4096
#define HH 64
#define NB 256
#define WSEG 2048          // u32 per (mat, seg): 256 threads * 8
#define WMAT 8192          // u32 per mat: 4 segs

typedef _Float16 h2  __attribute__((ext_vector_type(2)));
typedef uint32_t uv8 __attribute__((ext_vector_type(8)));

__device__ __forceinline__ h2 bch2(uint32_t u) { return __builtin_bit_cast(h2, u); }

template<int CTRL>
__device__ __forceinline__ float fdpp(float v) {
    return __builtin_bit_cast(float,
        __builtin_amdgcn_mov_dpp(__builtin_bit_cast(int, v), CTRL, 0xF, 0xF, true));
}
// quad_perm encodings: xor1=(1,0,3,2), xor2=(2,3,0,1), xor3=(3,2,1,0)
#define DPP_XOR1 0xB1
#define DPP_XOR2 0x4E
#define DPP_XOR3 0x1B
#define DPP_ROR4 0x124
#define DPP_ROR8 0x128

__device__ __forceinline__ float frcp(float x)  { return __builtin_amdgcn_rcpf(x); }
__device__ __forceinline__ float fexp2(float x) { return __builtin_amdgcn_exp2f(x); }

// Weight segment: 2x dwordx4 from pre-packed workspace. No cvt, no pack.
__device__ __forceinline__ uv8 load_pk(const uint32_t* __restrict__ p) {
    const uint4 a = *reinterpret_cast<const uint4*>(p);
    const uint4 b = *reinterpret_cast<const uint4*>(p + 4);
    uv8 r;
    r[0] = a.x; r[1] = a.y; r[2] = a.z; r[3] = a.w;
    r[4] = b.x; r[5] = b.y; r[6] = b.z; r[7] = b.w;
    return r;
}

// Opaque pin: asm results cannot be rematerialized -> forces VGPR residency.
__device__ __forceinline__ void pin(uv8& r) {
#pragma unroll
    for (int j = 0; j < 8; ++j) {
        uint32_t t = r[j];
        asm volatile("" : "+v"(t));
        r[j] = t;
    }
}

// 16 fp16 weights (8 packed u32) . 16 fp16 h (two uint4) -> fp32 acc
__device__ __forceinline__ float dotseg(uv8 w, uint4 a, uint4 b, float acc) {
    acc = __builtin_amdgcn_fdot2(bch2(w[0]), bch2(a.x), acc, false);
    acc = __builtin_amdgcn_fdot2(bch2(w[1]), bch2(a.y), acc, false);
    acc = __builtin_amdgcn_fdot2(bch2(w[2]), bch2(a.z), acc, false);
    acc = __builtin_amdgcn_fdot2(bch2(w[3]), bch2(a.w), acc, false);
    acc = __builtin_amdgcn_fdot2(bch2(w[4]), bch2(b.x), acc, false);
    acc = __builtin_amdgcn_fdot2(bch2(w[5]), bch2(b.y), acc, false);
    acc = __builtin_amdgcn_fdot2(bch2(w[6]), bch2(b.z), acc, false);
    acc = __builtin_amdgcn_fdot2(bch2(w[7]), bch2(b.w), acc, false);
    return acc;
}

// ---- prep: fp32 weights -> packed fp16 pairs, XOR-gate-row order, per-thread
// streaming layout: ws[((mat*4 + seg)*256 + k)*8 + j], k=(u<<2)|qt,
// seg i holds row (qt^i)*64+u, cols 16*qt + 2j (+1).
__global__ __launch_bounds__(256)
void prep_weights(const float* __restrict__ Whh0, const float* __restrict__ Wih1,
                  const float* __restrict__ Whh1, const float* __restrict__ Wih2,
                  const float* __restrict__ Whh2, uint32_t* __restrict__ ws)
{
    const int idx = blockIdx.x * 256 + threadIdx.x;   // 0..40959
    const int j   = idx & 7;
    const int k   = (idx >> 3) & 255;
    const int i   = (idx >> 11) & 3;
    const int mat = idx >> 13;                         // 0..4
    const int u = k >> 2, qt = k & 3;
    const int row = ((qt ^ i) << 6) + u;
    const int col = (qt << 4) + (j << 1);
    const float* M = (mat == 0) ? Whh0 : (mat == 1) ? Wih1
                   : (mat == 2) ? Whh1 : (mat == 3) ? Wih2 : Whh2;
    h2 t;
    t[0] = (_Float16)M[row * HH + col];
    t[1] = (_Float16)M[row * HH + col + 1];
    ws[idx] = __builtin_bit_cast(uint32_t, t);
}

__global__ __launch_bounds__(768)
__attribute__((amdgpu_waves_per_eu(1, 3)))
void lstm3_fused(
    const float* __restrict__ x,
    const float* __restrict__ Wih0,
    const float* __restrict__ bih0, const float* __restrict__ bhh0,
    const float* __restrict__ bih1, const float* __restrict__ bhh1,
    const float* __restrict__ bih2, const float* __restrict__ bhh2,
    const float* __restrict__ Wlin, const float* __restrict__ blin,
    const uint32_t* __restrict__ wpk,
    float* __restrict__ out)
{
    const int b   = blockIdx.x;
    const int tid = threadIdx.x;
    const int grp = tid >> 8;          // layer 0,1,2
    const int k   = tid & 255;
    const int u   = k >> 2;            // hidden unit
    const int qt  = k & 3;             // col quarter AND final gate index
    const int row = qt * HH + u;       // this thread's final gate row

    __shared__ __align__(16) float xrow[SQ];
    __shared__ __align__(16) uint4 hbf[2][3][8];   // [buf][layer][8x uint4 = 64 fp16]
    __shared__ __align__(16) float ybuf[2][16];    // per-row head partials

    for (int i = tid; i < SQ; i += 768) xrow[i] = x[b * SQ + i];
    if (tid < 48) ((uint4*)hbf)[tid] = make_uint4(0, 0, 0, 0);
    if (tid < 32) ((float*)ybuf)[tid] = 0.f;

    // ---- weights: pre-packed u32 from workspace, XOR gate-row order ----
    const int matA = (grp == 0) ? 0 : (grp == 1) ? 1 : 3;
    const int matB = (grp == 1) ? 2 : 4;
    const uint32_t* pWA = wpk + matA * WMAT + k * 8;
    uv8 wA0 = load_pk(pWA + 0 * WSEG);
    uv8 wA1 = load_pk(pWA + 1 * WSEG);
    uv8 wA2 = load_pk(pWA + 2 * WSEG);
    uv8 wA3 = load_pk(pWA + 3 * WSEG);
    pin(wA0); pin(wA1); pin(wA2); pin(wA3);
    uv8 wB0 = {}, wB1 = {}, wB2 = {}, wB3 = {};
    if (grp != 0) {
        const uint32_t* pWB = wpk + matB * WMAT + k * 8;
        wB0 = load_pk(pWB + 0 * WSEG);
        wB1 = load_pk(pWB + 1 * WSEG);
        wB2 = load_pk(pWB + 2 * WSEG);
        wB3 = load_pk(pWB + 3 * WSEG);
        pin(wB0); pin(wB1); pin(wB2); pin(wB3);
    }

    float bias = 0.f, wih0 = 0.f, wlin_u = 0.f;
    if (grp == 0) { bias = bih0[row] + bhh0[row]; wih0 = Wih0[row]; }
    else if (grp == 1) bias = bih1[row] + bhh1[row];
    else { bias = bih2[row] + bhh2[row]; if (qt == 0) wlin_u = Wlin[u]; }
    const float blin_v = blin[0];

    const int la = (grp == 2) ? 1 : 0;     // A-matvec h source layer
    const int lb = grp;                    // B-matvec h source layer (own)
    // Precomputed LDS pointers (literal rd indexes these -> imm offsets only)
    const uint4* pA[2] = { &hbf[0][la][2 * qt], &hbf[1][la][2 * qt] };
    const uint4* pB[2] = { &hbf[0][lb][2 * qt], &hbf[1][lb][2 * qt] };
    _Float16* pW[2] = { (_Float16*)&hbf[0][grp][0] + u, (_Float16*)&hbf[1][grp][0] + u };

    const float s1  = (qt == 2) ? 2.f : 1.f;            // tanh = 2*sigm(2x)-1
    const float o1  = (qt == 2) ? 1.f : 0.f;
    const float ms1 = -s1 * 1.44269504f;                // exp(-s1*g)=exp2(ms1*g)
    float cc = 0.f;                        // cell state (leaders qt==0)

    __syncthreads();

    auto tick = [&](int T, int rd) {
        const int wr = rd ^ 1;

        const uint4 a0 = pA[rd][0], a1 = pA[rd][1];
        float p0 = dotseg(wA0, a0, a1, 0.f);
        float p1 = dotseg(wA1, a0, a1, 0.f);
        float p2 = dotseg(wA2, a0, a1, 0.f);
        float p3 = dotseg(wA3, a0, a1, 0.f);
        if (grp != 0) {
            const uint4 c0 = pB[rd][0], c1 = pB[rd][1];
            p0 = dotseg(wB0, c0, c1, p0);
            p1 = dotseg(wB1, c0, c1, p1);
            p2 = dotseg(wB2, c0, c1, p2);
            p3 = dotseg(wB3, c0, c1, p3);
        }

        // XOR order (p_i = gate qt^i) -> add-only quad butterfly:
        // lane qt ends with the full sum of gate qt
        float g = (p0 + fdpp<DPP_XOR1>(p1))
                + fdpp<DPP_XOR2>(p2 + fdpp<DPP_XOR1>(p3));
        g += bias;
        if (grp == 0) g += wih0 * xrow[(T < SQ) ? T : 0];

        // activation + quad combine (DPP)
        const float t   = frcp(1.f + fexp2(ms1 * g));
        const float act = s1 * t - o1;     // sigm for i,f,o; tanh for g
        const float v1 = fdpp<DPP_XOR1>(act);
        const float v2 = fdpp<DPP_XOR2>(act);
        const float v3 = fdpp<DPP_XOR3>(act);

        const int step = T - grp;
        float yv = 0.f;
        if (qt == 0 && step >= 0 && step < SQ) {
            cc = v1 * cc + act * v2;       // sigm(f)*c + sigm(i)*tanh(g)
            float tc = fminf(fmaxf(cc, -15.f), 15.f);
            float e  = fexp2(tc * -2.88539008f);           // exp(-2*tc)
            float h  = v3 * ((1.f - e) * frcp(1.f + e));   // sigm(o)*tanh(c)
            *pW[wr] = (_Float16)h;
            if (grp == 2) yv = wlin_u * h;
            if (step == SQ - 1) {
                out[NB * SQ + grp * NB * HH + b * HH + u] = h;
                out[NB * SQ + 3 * NB * HH + grp * NB * HH + b * HH + u] = cc;
            }
        }
        if (grp == 2) {
            // head partials: quad + row sums (all DPP), 16 slots per buffer
            yv += fdpp<DPP_XOR1>(yv);
            yv += fdpp<DPP_XOR2>(yv);
            yv += fdpp<DPP_ROR4>(yv);
            yv += fdpp<DPP_ROR8>(yv);
            if ((k & 15) == 0) ybuf[rd][k >> 4] = yv;
        }
        if (grp == 0 && u == HH - 1) {
            // final head sum for step T-3 (u==63 quad of grp0 wave 3)
            const int sy = T - 3;
            if (sy >= 0 && sy < SQ) {
                const float4 v = ((const float4*)ybuf[rd ^ 1])[qt];
                float s = (v.x + v.y) + (v.z + v.w);
                s += fdpp<DPP_XOR1>(s);
                s += fdpp<DPP_XOR2>(s);
                if (qt == 3) out[b * SQ + sy] = s + blin_v;
            }
        }
        __syncthreads();
    };

    for (int T = 0; T < SQ + 4; T += 2) {  // ticks 0..4099 (needs 0..4098)
        tick(T, 0);
        tick(T + 1, 1);
    }
}

extern "C" void kernel_launch(void* const* d_in, const int* in_sizes, int n_in,
                              void* d_out, int out_size, void* d_ws, size_t ws_size,
                              hipStream_t stream) {
    const float* x    = (const float*)d_in[0];
    const float* Wih0 = (const float*)d_in[1];
    const float* Whh0 = (const float*)d_in[2];
    const float* bih0 = (const float*)d_in[3];
    const float* bhh0 = (const float*)d_in[4];
    const float* Wih1 = (const float*)d_in[5];
    const float* Whh1 = (const float*)d_in[6];
    const float* bih1 = (const float*)d_in[7];
    const float* bhh1 = (const float*)d_in[8];
    const float* Wih2 = (const float*)d_in[9];
    const float* Whh2 = (const float*)d_in[10];
    const float* bih2 = (const float*)d_in[11];
    const float* bhh2 = (const float*)d_in[12];
    const float* Wlin = (const float*)d_in[13];
    const float* blin = (const float*)d_in[14];
    float* out = (float*)d_out;

    uint32_t* wpk = (uint32_t*)d_ws;   // 40960 u32 = 160 KiB < ws_size
    prep_weights<<<160, 256, 0, stream>>>(Whh0, Wih1, Whh1, Wih2, Whh2, wpk);
    lstm3_fused<<<NB, 768, 0, stream>>>(x, Wih0, bih0, bhh0,
                                        bih1, bhh1, bih2, bhh2,
                                        Wlin, blin, wpk, out);
}